// Round 2
// baseline (8651.827 us; speedup 1.0000x reference)
//
#include <hip/hip_runtime.h>

// ---------------------------------------------------------------------------
// Persistent fused LSTM for MI355X (gfx950).
//
// Decomposition: 256 blocks = 8 batch-groups (blockIdx&7, XCD-aligned under
// the measured round-robin dispatch — perf heuristic only, NOT a correctness
// assumption) x 32 column-blocks (blockIdx>>3). Block owns 64 batch rows x
// 16 h-cols. Weights (4 gates, fp16, transposed [n][k]) stay resident in LDS
// for all 256 timesteps. x-projection + bias folded into the GEMM via
// K-augmentation: K = 512 (h) + 10 (xe) + 1 (bias via 1.0) + pad = 17
// k-steps of 32. Cell state c: fp32 registers, never touches memory.
// h exchanged via 2 ping-pong fp16 global buffers + per-(group,step)
// write-once MAGIC flag slots in d_ws (ws poison 0xAA != MAGIC, so no
// counter init needed; write-once => no reset race on graph replay).
// Cross-XCD safety: __threadfence() (agent scope) on gfx950 performs L2
// writeback/invalidate, so the h exchange is correct under ANY block->XCD
// placement; blockIdx&7 grouping only makes it fast when round-robin holds.
// ---------------------------------------------------------------------------

#define BATCH  512
#define TSTEPS 256
#define HDIM   512
#define EDIM   10
#define NCLS   10

#define GROUPS 8
#define CBLK   32     // column blocks per group
#define MBLK   64     // batch rows per group
#define NBLK   64     // gate-cols per block = 4 gates * 16 hcols
#define PITCH  552    // LDS row pitch (elems): 1104B = 69*16B (69 odd -> 2-way max on b128)
#define MAGICF 0x13572468u

typedef _Float16 half_t;
typedef _Float16 f16x8 __attribute__((ext_vector_type(8)));
typedef float    f32x4 __attribute__((ext_vector_type(4)));

__device__ __forceinline__ float sigm_f(float x) {
    return 1.f / (1.f + __expf(-x));
}
__device__ __forceinline__ float tanh_f(float x) {
    x = fminf(fmaxf(x, -15.f), 15.f);   // avoid inf/inf
    float e = __expf(2.f * x);
    return (e - 1.f) / (e + 1.f);
}

// Spin until all 32 column-blocks of this group set their MAGIC slot for a
// step, then acquire-fence (agent scope) so subsequent h reads are fresh.
__device__ __forceinline__ void group_wait(const unsigned int* fl, int wave, int lane) {
    if (wave == 0) {
        for (;;) {
            unsigned int v = MAGICF;
            if (lane < 32)
                v = __hip_atomic_load(fl + lane, __ATOMIC_RELAXED, __HIP_MEMORY_SCOPE_AGENT);
            if (__all(v == MAGICF)) break;
            __builtin_amdgcn_s_sleep(2);
        }
    }
    __syncthreads();
    __threadfence();   // acquire side: invalidate stale cached h lines
}

__global__ __launch_bounds__(256, 1) void lstm_persist(
    const int* __restrict__ x, const float* __restrict__ emb,
    const float* __restrict__ Wgx, const float* __restrict__ Wgh, const float* __restrict__ bg,
    const float* __restrict__ Wix, const float* __restrict__ Wih, const float* __restrict__ bi,
    const float* __restrict__ Wfx, const float* __restrict__ Wfh, const float* __restrict__ bf,
    const float* __restrict__ Wox, const float* __restrict__ Woh, const float* __restrict__ bo,
    const float* __restrict__ Wph, const float* __restrict__ bp,
    float* __restrict__ out, half_t* __restrict__ h0buf, half_t* __restrict__ h1buf,
    unsigned int* __restrict__ flags)
{
    __shared__ half_t Alds[MBLK * PITCH];   // h tile + xe augmentation (70656 B)
    __shared__ half_t Blds[NBLK * PITCH];   // W^T slice: [n][k]         (70656 B)
    __shared__ float  zlds[2 * 64 * 16];    // gate z exchange            (8192 B)

    const int tid  = threadIdx.x;
    const int wave = tid >> 6, lane = tid & 63;
    const int wm   = wave >> 1, wn = wave & 1;      // 2x2 wave grid over 64x64 tile
    const int g    = blockIdx.x & 7;                // batch group (XCD-aligned)
    const int j    = blockIdx.x >> 3;               // column block 0..31

    // ---- one-time init: weights^T -> LDS (fp16), zero pads ----
    #pragma unroll
    for (int gate = 0; gate < 4; ++gate) {
        const float* W = (gate == 0) ? Wgh : (gate == 1) ? Wih : (gate == 2) ? Wfh : Woh;
        for (int idx = tid; idx < HDIM * 16; idx += 256) {
            int c = idx & 15, k = idx >> 4;       // coalesced 64B global reads
            Blds[(gate * 16 + c) * PITCH + k] = (half_t)W[k * HDIM + j * 16 + c];
        }
    }
    if (tid < NBLK) {
        int gate = tid >> 4, c = tid & 15, hcol = j * 16 + c;
        const float* Wx = (gate == 0) ? Wgx : (gate == 1) ? Wix : (gate == 2) ? Wfx : Wox;
        const float* bb = (gate == 0) ? bg  : (gate == 1) ? bi  : (gate == 2) ? bf  : bo;
        #pragma unroll
        for (int e = 0; e < EDIM; ++e)
            Blds[tid * PITCH + 512 + e] = (half_t)Wx[e * HDIM + hcol];
        Blds[tid * PITCH + 522] = (half_t)bb[hcol];    // bias row (A has 1.0 there)
        for (int k = 523; k < PITCH; ++k) Blds[tid * PITCH + k] = (half_t)0.f;
    }
    if (tid < MBLK) {
        for (int k = 523; k < PITCH; ++k) Alds[tid * PITCH + k] = (half_t)0.f;
    }

    float c_state[8];
    #pragma unroll
    for (int i = 0; i < 8; ++i) c_state[i] = 0.f;

    for (int t = 0; t < TSTEPS; ++t) {
        // xe staging (x/emb are immutable inputs -> safe before the fence;
        // only wave 0 writes this region, reads happen after __syncthreads)
        if (tid < MBLK) {
            int m = tid;
            int idx = x[(g * MBLK + m) * TSTEPS + t];
            const float* er = emb + idx * EDIM;
            #pragma unroll
            for (int e = 0; e < EDIM; ++e)
                Alds[m * PITCH + 512 + e] = (half_t)er[e];
            Alds[m * PITCH + 522] = (half_t)1.f;
        }
        if (t > 0) {
            group_wait(flags + (g * TSTEPS + (t - 1)) * 32, wave, lane);
            // stage h_t (fp16, straight copy): wave w loads rows [16w,16w+16)
            const half_t* hsrc = ((t & 1) ? h1buf : h0buf) + g * MBLK * HDIM;
            #pragma unroll
            for (int i = 0; i < 16; ++i) {
                int m = wave * 16 + i;
                f16x8 v = *(const f16x8*)(hsrc + m * HDIM + lane * 8);
                *(f16x8*)&Alds[m * PITCH + lane * 8] = v;
            }
        }
        __syncthreads();

        // ---- GEMM 64x64xK: n = gate*16 + hc, so n-frag == gate ----
        f32x4 acc00 = {0.f, 0.f, 0.f, 0.f};   // [mf=0][wn-gate pair 0]
        f32x4 acc01 = {0.f, 0.f, 0.f, 0.f};   // [mf=0][wn-gate pair 1]
        f32x4 acc10 = {0.f, 0.f, 0.f, 0.f};
        f32x4 acc11 = {0.f, 0.f, 0.f, 0.f};
        const int row = lane & 15, kq = lane >> 4;
        for (int ks = (t == 0) ? 16 : 0; ks <= 16; ++ks) {   // t=0: h==0, only x+bias part
            int ko = ks * 32 + kq * 8;
            f16x8 a0 = *(const f16x8*)&Alds[(wm * 32 +      row) * PITCH + ko];
            f16x8 a1 = *(const f16x8*)&Alds[(wm * 32 + 16 + row) * PITCH + ko];
            f16x8 b0 = *(const f16x8*)&Blds[(wn * 32 +      row) * PITCH + ko];
            f16x8 b1 = *(const f16x8*)&Blds[(wn * 32 + 16 + row) * PITCH + ko];
            acc00 = __builtin_amdgcn_mfma_f32_16x16x32_f16(a0, b0, acc00, 0, 0, 0);
            acc01 = __builtin_amdgcn_mfma_f32_16x16x32_f16(a0, b1, acc01, 0, 0, 0);
            acc10 = __builtin_amdgcn_mfma_f32_16x16x32_f16(a1, b0, acc10, 0, 0, 0);
            acc11 = __builtin_amdgcn_mfma_f32_16x16x32_f16(a1, b1, acc11, 0, 0, 0);
        }

        // waves wn==1 hold gates f,o -> push z through LDS to partner lane
        if (wn == 1) {
            float* zp = zlds + (wm * 64 + lane) * 16;
            *(f32x4*)(zp + 0)  = acc00;    // mf=0, gate f
            *(f32x4*)(zp + 4)  = acc01;    // mf=0, gate o
            *(f32x4*)(zp + 8)  = acc10;    // mf=1, gate f
            *(f32x4*)(zp + 12) = acc11;    // mf=1, gate o
        }
        __syncthreads();

        if (wn == 0) {
            const float* zp = zlds + (wm * 64 + lane) * 16;
            half_t* hdst = (t & 1) ? h0buf : h1buf;    // step t writes buffer (t+1)&1
            const int hc = lane & 15;
            #pragma unroll
            for (int mf = 0; mf < 2; ++mf) {
                f32x4 zgv = mf ? acc10 : acc00;        // gate 0 (g)
                f32x4 ziv = mf ? acc11 : acc01;        // gate 1 (i)
                #pragma unroll
                for (int r = 0; r < 4; ++r) {
                    float zg = zgv[r], zi = ziv[r];
                    float zf = zp[mf * 8 + r];         // gate 2 (f)
                    float zo = zp[mf * 8 + 4 + r];     // gate 3 (o)
                    float gv = tanh_f(zg), iv = sigm_f(zi);
                    float fv = sigm_f(zf), ov = sigm_f(zo);
                    int ci = mf * 4 + r;
                    float cv = gv * iv + c_state[ci] * fv;
                    c_state[ci] = cv;
                    float hv = tanh_f(cv) * ov;
                    int m = wm * 32 + mf * 16 + (lane >> 4) * 4 + r;  // C/D: row=(l>>4)*4+r
                    hdst[(g * MBLK + m) * HDIM + j * 16 + hc] = (half_t)hv;
                }
            }
            __threadfence();   // release our h stores to agent scope (L2 wb)
        }
        __syncthreads();
        if (tid == 0)
            __hip_atomic_store(flags + (g * TSTEPS + t) * 32 + j, MAGICF,
                               __ATOMIC_RELEASE, __HIP_MEMORY_SCOPE_AGENT);
    }

    // ---- epilogue: out = h_T @ Wph + bp; block handles rows 64g+2j, +1 ----
    group_wait(flags + (g * TSTEPS + (TSTEPS - 1)) * 32, wave, lane);
    if (wave == 0) {
        const half_t* hT = h0buf;                  // step 255 (odd) wrote buffer 0
        int rb0 = g * MBLK + j * 2;
        float hreg[2][8];
        #pragma unroll
        for (int i = 0; i < 2; ++i) {
            #pragma unroll
            for (int kk = 0; kk < 8; ++kk)
                hreg[i][kk] = (float)hT[(rb0 + i) * HDIM + kk * 64 + lane];
        }
        #pragma unroll
        for (int i = 0; i < 2; ++i) {
            for (int cc = 0; cc < NCLS; ++cc) {
                float s = 0.f;
                #pragma unroll
                for (int kk = 0; kk < 8; ++kk)
                    s += hreg[i][kk] * Wph[(kk * 64 + lane) * NCLS + cc];
                #pragma unroll
                for (int off = 32; off > 0; off >>= 1) s += __shfl_down(s, off);
                if (lane == 0) out[(rb0 + i) * NCLS + cc] = s + bp[cc];
            }
        }
    }
}

extern "C" void kernel_launch(void* const* d_in, const int* in_sizes, int n_in,
                              void* d_out, int out_size, void* d_ws, size_t ws_size,
                              hipStream_t stream) {
    (void)in_sizes; (void)n_in; (void)out_size; (void)ws_size;
    const int*   x   = (const int*)d_in[0];
    const float* emb = (const float*)d_in[1];
    const float* Wgx = (const float*)d_in[2];
    const float* Wgh = (const float*)d_in[3];
    const float* bg  = (const float*)d_in[4];
    const float* Wix = (const float*)d_in[5];
    const float* Wih = (const float*)d_in[6];
    const float* bi  = (const float*)d_in[7];
    const float* Wfx = (const float*)d_in[8];
    const float* Wfh = (const float*)d_in[9];
    const float* bf  = (const float*)d_in[10];
    const float* Wox = (const float*)d_in[11];
    const float* Woh = (const float*)d_in[12];
    const float* bo  = (const float*)d_in[13];
    const float* Wph = (const float*)d_in[14];
    const float* bp  = (const float*)d_in[15];
    float* out = (float*)d_out;

    // ws layout: h ping-pong (2 x 512x512 fp16 = 1 MB) + flags (256 KB)
    half_t* h0 = (half_t*)d_ws;
    half_t* h1 = h0 + BATCH * HDIM;
    unsigned int* flags = (unsigned int*)((char*)d_ws + 2 * BATCH * HDIM * sizeof(half_t));

    void* args[] = { &x, &emb, &Wgx, &Wgh, &bg, &Wix, &Wih, &bi, &Wfx, &Wfh, &bf,
                     &Wox, &Woh, &bo, &Wph, &bp, &out, &h0, &h1, &flags };
    hipLaunchCooperativeKernel(reinterpret_cast<const void*>(lstm_persist),
                               dim3(GROUPS * CBLK), dim3(256), args, 0u, stream);
}

// Round 6
// 2393.043 us; speedup vs baseline: 3.6154x; 3.6154x over previous
//
#include <hip/hip_runtime.h>

// ---------------------------------------------------------------------------
// Persistent fused LSTM for MI355X (gfx950).  Round 6 submission
// (= Round-4/5 kernel, unchanged; Rounds 3-5 never ran — GPU acquisition
// timeouts. Single datapoint remains Round 2. No new evidence => no blind
// mutation).
//
// Round-2 post-mortem: per-thread __threadfence() (buffer_wbl2 sc1) pushed
// the 512 KB/step h exchange to HBM synchronously -> 28 us/step writeback
// (WRITE_SIZE == h bytes, hbm_gbps == 18, dur 8.65 ms). Fix: no cache
// maintenance at all. h + flags move via relaxed AGENT-scope atomics
// (cache-bypass -> coherent at the memory fabric / Infinity Cache, where
// the 1 MB ping-pong lives). Ordering: producers drain vmcnt (explicit
// s_waitcnt + barrier), THEN tid0 sets the flag -> flag visible implies h
// at the coherence point. Consumers spin on flags (compiler fence after
// the spin), then issue coherent h loads.
//
// Hardenings (vs the Round-3 draft that never ran):
//  - no 16-bit atomics anywhere (lowering risk): h stores staged through
//    LDS hstage[64][20] then ONE 64-bit relaxed agent atomic store per
//    thread per step; epilogue reads h via 64-bit atomics too.
//  - asm compiler fence after flag spin (no hoisting of relaxed h loads).
//
// Decomposition: 256 blocks = 8 batch-groups (blockIdx&7, XCD-aligned under
// round-robin dispatch — perf heuristic only) x 32 column-blocks. Block owns
// 64 batch rows x 16 h-cols. Weights (4 gates, fp16, [n][k]) resident in LDS
// for all 256 steps. x-proj + bias folded into GEMM via K-augmentation
// (K = 512 h + 10 xe + 1 bias + pad = 17 k-steps of 32). Cell state c in
// fp32 registers. Flags: write-once MAGIC slots in d_ws (poison 0xAA !=
// MAGIC -> no init, no reset race on graph replay).
// ---------------------------------------------------------------------------

#define BATCH  512
#define TSTEPS 256
#define HDIM   512
#define EDIM   10
#define NCLS   10

#define GROUPS 8
#define CBLK   32     // column blocks per group
#define MBLK   64     // batch rows per group
#define NBLK   64     // gate-cols per block = 4 gates * 16 hcols
#define PITCH  552    // LDS row pitch (elems): 1104B = 69*16B (69 odd -> benign on b128)
#define HSP    20     // hstage pitch (halfs): 40B rows -> 8B-aligned, banks spread
#define MAGICF 0x13572468u

typedef _Float16 half_t;
typedef _Float16 f16x8 __attribute__((ext_vector_type(8)));
typedef float    f32x4 __attribute__((ext_vector_type(4)));
typedef unsigned long long ull_t;

__device__ __forceinline__ float sigm_f(float x) {
    return 1.f / (1.f + __expf(-x));
}
__device__ __forceinline__ float tanh_f(float x) {
    x = fminf(fmaxf(x, -15.f), 15.f);   // avoid inf/inf
    float e = __expf(2.f * x);
    return (e - 1.f) / (e + 1.f);
}

// Spin until all 32 column-blocks of this group set their MAGIC slot for a
// step. Relaxed agent loads bypass stale caches; subsequent h reads are
// themselves agent-coherent atomics. Compiler fence stops any hoisting.
__device__ __forceinline__ void group_wait(const unsigned int* fl, int wave, int lane) {
    if (wave == 0) {
        for (;;) {
            unsigned int v = MAGICF;
            if (lane < 32)
                v = __hip_atomic_load(fl + lane, __ATOMIC_RELAXED, __HIP_MEMORY_SCOPE_AGENT);
            if (__all(v == MAGICF)) break;
            __builtin_amdgcn_s_sleep(1);
        }
    }
    asm volatile("" ::: "memory");
    __syncthreads();
}

__global__ __launch_bounds__(256, 1) void lstm_persist(
    const int* __restrict__ x, const float* __restrict__ emb,
    const float* __restrict__ Wgx, const float* __restrict__ Wgh, const float* __restrict__ bg,
    const float* __restrict__ Wix, const float* __restrict__ Wih, const float* __restrict__ bi,
    const float* __restrict__ Wfx, const float* __restrict__ Wfh, const float* __restrict__ bf,
    const float* __restrict__ Wox, const float* __restrict__ Woh, const float* __restrict__ bo,
    const float* __restrict__ Wph, const float* __restrict__ bp,
    float* __restrict__ out, half_t* __restrict__ h0buf, half_t* __restrict__ h1buf,
    unsigned int* __restrict__ flags)
{
    __shared__ half_t Alds[MBLK * PITCH];    // h tile + xe augmentation (70656 B)
    __shared__ half_t Blds[NBLK * PITCH];    // W^T slice: [n][k]         (70656 B)
    __shared__ float  zlds[2 * 64 * 16];     // gate z exchange            (8192 B)
    __shared__ half_t hstage[MBLK * HSP];    // h tile staging             (2560 B)

    const int tid  = threadIdx.x;
    const int wave = tid >> 6, lane = tid & 63;
    const int wm   = wave >> 1, wn = wave & 1;      // 2x2 wave grid over 64x64 tile
    const int g    = blockIdx.x & 7;                // batch group (XCD-aligned)
    const int j    = blockIdx.x >> 3;               // column block 0..31

    // ---- one-time init: weights^T -> LDS (fp16), zero pads ----
    #pragma unroll
    for (int gate = 0; gate < 4; ++gate) {
        const float* W = (gate == 0) ? Wgh : (gate == 1) ? Wih : (gate == 2) ? Wfh : Woh;
        for (int idx = tid; idx < HDIM * 16; idx += 256) {
            int c = idx & 15, k = idx >> 4;       // coalesced 64B global reads
            Blds[(gate * 16 + c) * PITCH + k] = (half_t)W[k * HDIM + j * 16 + c];
        }
    }
    if (tid < NBLK) {
        int gate = tid >> 4, c = tid & 15, hcol = j * 16 + c;
        const float* Wx = (gate == 0) ? Wgx : (gate == 1) ? Wix : (gate == 2) ? Wfx : Wox;
        const float* bb = (gate == 0) ? bg  : (gate == 1) ? bi  : (gate == 2) ? bf  : bo;
        #pragma unroll
        for (int e = 0; e < EDIM; ++e)
            Blds[tid * PITCH + 512 + e] = (half_t)Wx[e * HDIM + hcol];
        Blds[tid * PITCH + 522] = (half_t)bb[hcol];    // bias row (A has 1.0 there)
        for (int k = 523; k < PITCH; ++k) Blds[tid * PITCH + k] = (half_t)0.f;
    }
    if (tid < MBLK) {
        for (int k = 523; k < PITCH; ++k) Alds[tid * PITCH + k] = (half_t)0.f;
    }

    float c_state[8];
    #pragma unroll
    for (int i = 0; i < 8; ++i) c_state[i] = 0.f;

    for (int t = 0; t < TSTEPS; ++t) {
        // xe staging (x/emb immutable inputs, plain cached loads; wave 0 does
        // this BEFORE its spin so it overlaps nothing critical)
        if (tid < MBLK) {
            int m = tid;
            int idx = x[(g * MBLK + m) * TSTEPS + t];
            const float* er = emb + idx * EDIM;
            #pragma unroll
            for (int e = 0; e < EDIM; ++e)
                Alds[m * PITCH + 512 + e] = (half_t)er[e];
            Alds[m * PITCH + 522] = (half_t)1.f;
        }
        if (t > 0) {
            group_wait(flags + (g * TSTEPS + (t - 1)) * 32, wave, lane);
            // stage h_t: coherent (agent) 8B loads from LLC ping-pong -> LDS
            const ull_t* hsrc = (const ull_t*)(((t & 1) ? h1buf : h0buf)
                                               + (size_t)g * MBLK * HDIM);
            #pragma unroll
            for (int i = 0; i < 16; ++i) {
                int m = wave * 16 + i;
                ull_t v0 = __hip_atomic_load(hsrc + m * 128 + lane * 2,
                                             __ATOMIC_RELAXED, __HIP_MEMORY_SCOPE_AGENT);
                ull_t v1 = __hip_atomic_load(hsrc + m * 128 + lane * 2 + 1,
                                             __ATOMIC_RELAXED, __HIP_MEMORY_SCOPE_AGENT);
                ull_t* dst = (ull_t*)&Alds[m * PITCH + lane * 8];
                dst[0] = v0; dst[1] = v1;
            }
        }
        __syncthreads();

        // ---- GEMM 64x64xK: n = gate*16 + hc ----
        f32x4 acc00 = {0.f, 0.f, 0.f, 0.f};
        f32x4 acc01 = {0.f, 0.f, 0.f, 0.f};
        f32x4 acc10 = {0.f, 0.f, 0.f, 0.f};
        f32x4 acc11 = {0.f, 0.f, 0.f, 0.f};
        const int row = lane & 15, kq = lane >> 4;
        for (int ks = (t == 0) ? 16 : 0; ks <= 16; ++ks) {   // t=0: h==0, x+bias only
            int ko = ks * 32 + kq * 8;
            f16x8 a0 = *(const f16x8*)&Alds[(wm * 32 +      row) * PITCH + ko];
            f16x8 a1 = *(const f16x8*)&Alds[(wm * 32 + 16 + row) * PITCH + ko];
            f16x8 b0 = *(const f16x8*)&Blds[(wn * 32 +      row) * PITCH + ko];
            f16x8 b1 = *(const f16x8*)&Blds[(wn * 32 + 16 + row) * PITCH + ko];
            acc00 = __builtin_amdgcn_mfma_f32_16x16x32_f16(a0, b0, acc00, 0, 0, 0);
            acc01 = __builtin_amdgcn_mfma_f32_16x16x32_f16(a0, b1, acc01, 0, 0, 0);
            acc10 = __builtin_amdgcn_mfma_f32_16x16x32_f16(a1, b0, acc10, 0, 0, 0);
            acc11 = __builtin_amdgcn_mfma_f32_16x16x32_f16(a1, b1, acc11, 0, 0, 0);
        }

        // waves wn==1 hold gates f,o -> push z through LDS to partner lane
        if (wn == 1) {
            float* zp = zlds + (wm * 64 + lane) * 16;
            *(f32x4*)(zp + 0)  = acc00;    // mf=0, gate f
            *(f32x4*)(zp + 4)  = acc01;    // mf=0, gate o
            *(f32x4*)(zp + 8)  = acc10;    // mf=1, gate f
            *(f32x4*)(zp + 12) = acc11;    // mf=1, gate o
        }
        __syncthreads();

        // waves wn==0: activations + cell update -> hstage (LDS, fp16)
        if (wn == 0) {
            const float* zp = zlds + (wm * 64 + lane) * 16;
            const int hc = lane & 15;
            #pragma unroll
            for (int mf = 0; mf < 2; ++mf) {
                f32x4 zgv = mf ? acc10 : acc00;        // gate 0 (g)
                f32x4 ziv = mf ? acc11 : acc01;        // gate 1 (i)
                #pragma unroll
                for (int r = 0; r < 4; ++r) {
                    float zg = zgv[r], zi = ziv[r];
                    float zf = zp[mf * 8 + r];         // gate 2 (f)
                    float zo = zp[mf * 8 + 4 + r];     // gate 3 (o)
                    float gv = tanh_f(zg), iv = sigm_f(zi);
                    float fv = sigm_f(zf), ov = sigm_f(zo);
                    int ci = mf * 4 + r;
                    float cv = gv * iv + c_state[ci] * fv;
                    c_state[ci] = cv;
                    float hv = tanh_f(cv) * ov;
                    int m = wm * 32 + mf * 16 + (lane >> 4) * 4 + r;  // C/D: row=(l>>4)*4+r
                    hstage[m * HSP + hc] = (half_t)hv;
                }
            }
        }
        __syncthreads();

        // all 256 threads: one coherent 8B store each (4 cols x fp16)
        {
            int mrow = tid >> 2, part = tid & 3;
            ull_t v = *(const ull_t*)&hstage[mrow * HSP + part * 4];
            ull_t* hd = (ull_t*)((t & 1) ? h0buf : h1buf);   // step t -> buffer (t+1)&1
            __hip_atomic_store(hd + (size_t)(g * MBLK + mrow) * 128 + j * 4 + part, v,
                               __ATOMIC_RELAXED, __HIP_MEMORY_SCOPE_AGENT);
            asm volatile("s_waitcnt vmcnt(0)" ::: "memory");  // at LLC before barrier
        }
        __syncthreads();
        if (tid == 0)
            __hip_atomic_store(flags + (g * TSTEPS + t) * 32 + j, MAGICF,
                               __ATOMIC_RELAXED, __HIP_MEMORY_SCOPE_AGENT);
    }

    // ---- epilogue: out = h_T @ Wph + bp; block handles rows 64g+2j, +1 ----
    group_wait(flags + (g * TSTEPS + (TSTEPS - 1)) * 32, wave, lane);
    if (wave == 0) {
        const ull_t* hT = (const ull_t*)h0buf;     // step 255 (odd) wrote buffer 0
        int rb0 = g * MBLK + j * 2;
        union { ull_t u; half_t h[4]; } p0, p1;
        #pragma unroll
        for (int i = 0; i < 2; ++i) {
            p0.u = __hip_atomic_load(hT + (size_t)(rb0 + i) * 128 + lane * 2,
                                     __ATOMIC_RELAXED, __HIP_MEMORY_SCOPE_AGENT);
            p1.u = __hip_atomic_load(hT + (size_t)(rb0 + i) * 128 + lane * 2 + 1,
                                     __ATOMIC_RELAXED, __HIP_MEMORY_SCOPE_AGENT);
            float hreg[8];
            #pragma unroll
            for (int kk = 0; kk < 4; ++kk) { hreg[kk] = (float)p0.h[kk]; hreg[4 + kk] = (float)p1.h[kk]; }
            for (int cc = 0; cc < NCLS; ++cc) {
                float s = 0.f;
                #pragma unroll
                for (int kk = 0; kk < 8; ++kk)
                    s += hreg[kk] * Wph[(lane * 8 + kk) * NCLS + cc];
                #pragma unroll
                for (int off = 32; off > 0; off >>= 1) s += __shfl_down(s, off);
                if (lane == 0) out[(rb0 + i) * NCLS + cc] = s + bp[cc];
            }
        }
    }
}

extern "C" void kernel_launch(void* const* d_in, const int* in_sizes, int n_in,
                              void* d_out, int out_size, void* d_ws, size_t ws_size,
                              hipStream_t stream) {
    (void)in_sizes; (void)n_in; (void)out_size; (void)ws_size;
    const int*   x   = (const int*)d_in[0];
    const float* emb = (const float*)d_in[1];
    const float* Wgx = (const float*)d_in[2];
    const float* Wgh = (const float*)d_in[3];
    const float* bg  = (const float*)d_in[4];
    const float* Wix = (const float*)d_in[5];
    const float* Wih = (const float*)d_in[6];
    const float* bi  = (const float*)d_in[7];
    const float* Wfx = (const float*)d_in[8];
    const float* Wfh = (const float*)d_in[9];
    const float* bf  = (const float*)d_in[10];
    const float* Wox = (const float*)d_in[11];
    const float* Woh = (const float*)d_in[12];
    const float* bo  = (const float*)d_in[13];
    const float* Wph = (const float*)d_in[14];
    const float* bp  = (const float*)d_in[15];
    float* out = (float*)d_out;

    // ws layout: h ping-pong (2 x 512x512 fp16 = 1 MB) + flags (256 KB)
    half_t* h0 = (half_t*)d_ws;
    half_t* h1 = h0 + BATCH * HDIM;
    unsigned int* flags = (unsigned int*)((char*)d_ws + 2 * BATCH * HDIM * sizeof(half_t));

    void* args[] = { &x, &emb, &Wgx, &Wgh, &bg, &Wix, &Wih, &bi, &Wfx, &Wfh, &bf,
                     &Wox, &Woh, &bo, &Wph, &bp, &out, &h0, &h1, &flags };
    hipLaunchCooperativeKernel(reinterpret_cast<const void*>(lstm_persist),
                               dim3(GROUPS * CBLK), dim3(256), args, 0u, stream);
}